// Round 13
// baseline (151.637 us; speedup 1.0000x reference)
//
#include <hip/hip_runtime.h>
#include <hip/hip_bf16.h>

typedef unsigned short u16;
typedef int i32x4 __attribute__((ext_vector_type(4)));
typedef signed char s8;

#define NB_RED 256

// ---------------- min/max reduction (4 tensors) ----------------
__global__ void k_minmax_partial(const float* __restrict__ x, const float* __restrict__ h,
                                 const float* __restrict__ wi, const float* __restrict__ wh,
                                 float* __restrict__ partials) {
    int t = blockIdx.y;
    const float* p = (t == 0) ? x : (t == 1) ? h : (t == 2) ? wi : wh;
    int n4 = ((t < 2) ? (8192 * 1024) : (4096 * 1024)) >> 2;
    float mn = 3.4e38f, mx = -3.4e38f;
    const float4* p4 = (const float4*)p;
    for (int i = blockIdx.x * blockDim.x + threadIdx.x; i < n4; i += gridDim.x * blockDim.x) {
        float4 v = p4[i];
        mn = fminf(mn, fminf(fminf(v.x, v.y), fminf(v.z, v.w)));
        mx = fmaxf(mx, fmaxf(fmaxf(v.x, v.y), fmaxf(v.z, v.w)));
    }
    for (int d = 1; d < 64; d <<= 1) {
        mn = fminf(mn, __shfl_xor(mn, d));
        mx = fmaxf(mx, __shfl_xor(mx, d));
    }
    __shared__ float smn[4], smx[4];
    int wv = threadIdx.x >> 6;
    if ((threadIdx.x & 63) == 0) { smn[wv] = mn; smx[wv] = mx; }
    __syncthreads();
    if (threadIdx.x == 0) {
        mn = fminf(fminf(smn[0], smn[1]), fminf(smn[2], smn[3]));
        mx = fmaxf(fmaxf(smx[0], smx[1]), fmaxf(smx[2], smx[3]));
        partials[(t * NB_RED + blockIdx.x) * 2 + 0] = mn;
        partials[(t * NB_RED + blockIdx.x) * 2 + 1] = mx;
    }
}

__global__ void k_minmax_final(const float* __restrict__ partials, const int* __restrict__ nbits,
                               float* __restrict__ params) {
    int t = blockIdx.x;
    int tid = threadIdx.x;
    float mn = partials[(t * NB_RED + tid) * 2 + 0];
    float mx = partials[(t * NB_RED + tid) * 2 + 1];
    for (int d = 1; d < 64; d <<= 1) {
        mn = fminf(mn, __shfl_xor(mn, d));
        mx = fmaxf(mx, __shfl_xor(mx, d));
    }
    __shared__ float smn[4], smx[4];
    int wv = tid >> 6;
    if ((tid & 63) == 0) { smn[wv] = mn; smx[wv] = mx; }
    __syncthreads();
    if (tid == 0) {
        mn = fminf(fminf(smn[0], smn[1]), fminf(smn[2], smn[3]));
        mx = fmaxf(fmaxf(smx[0], smx[1]), fmaxf(smx[2], smx[3]));
        float qmax = (float)((1u << (*nbits)) - 1u);
        params[t * 2 + 0] = mn;
        params[t * 2 + 1] = (mx - mn) / qmax;
    }
}

static __device__ __forceinline__ int block_reduce_i(int v, int tid) {
    for (int d = 1; d < 64; d <<= 1) v += __shfl_xor(v, d);
    __shared__ int sred[4];
    if ((tid & 63) == 0) sred[tid >> 6] = v;
    __syncthreads();
    return sred[0] + sred[1] + sred[2] + sred[3];
}

// ---- fused quantize (x|h -> A8, W_in|W_h -> W8 permuted) + bias ----
// blocks [0,16384): A rows; [16384,24576): W rows; [24576,24592): bias.
__global__ void k_quant(const float* __restrict__ x, const float* __restrict__ h,
                        const float* __restrict__ wi, const float* __restrict__ wh,
                        const float* __restrict__ params,
                        const float* __restrict__ b_in, const float* __restrict__ b_h,
                        s8* __restrict__ A8, s8* __restrict__ W8,
                        float* __restrict__ Rax, float* __restrict__ Rah,
                        float* __restrict__ Rbi, float* __restrict__ Rbh,
                        float* __restrict__ bc) {
    int b = blockIdx.x;
    int t = threadIdx.x;
    if (b < 16384) {
        int tsel = b >> 13;            // 0: x, 1: h
        int row = b & 8191;
        const float* src = tsel ? h : x;
        float mn = params[tsel * 2 + 0], s = params[tsel * 2 + 1];
        float4 v = ((const float4*)(src + (size_t)row * 1024))[t];
        int k0 = (int)fminf(255.f, fmaxf(0.f, rintf((v.x - mn) / s)));
        int k1 = (int)fminf(255.f, fmaxf(0.f, rintf((v.y - mn) / s)));
        int k2 = (int)fminf(255.f, fmaxf(0.f, rintf((v.z - mn) / s)));
        int k3 = (int)fminf(255.f, fmaxf(0.f, rintf((v.w - mn) / s)));
        unsigned p = ((unsigned)((k0 - 128) & 0xff)) | ((unsigned)((k1 - 128) & 0xff) << 8) |
                     ((unsigned)((k2 - 128) & 0xff) << 16) | ((unsigned)((k3 - 128) & 0xff) << 24);
        *(unsigned*)(A8 + (size_t)row * 2048 + tsel * 1024 + t * 4) = p;
        int sum = block_reduce_i(k0 + k1 + k2 + k3 - 512, t);
        if (t == 0) (tsel ? Rah : Rax)[row] = (float)sum;
    } else if (b < 24576) {
        int bb = b - 16384;
        int tsel = bb >> 12;           // 0: W_in, 1: W_h
        int row = bb & 4095;           // original row g*1024+j
        const float* src = tsel ? wh : wi;
        float mn = params[(2 + tsel) * 2 + 0], s = params[(2 + tsel) * 2 + 1];
        int g = row >> 10, j = row & 1023;
        int prow = (j >> 4) * 64 + g * 16 + (j & 15);
        float4 v = ((const float4*)(src + (size_t)row * 1024))[t];
        int k0 = (int)fminf(255.f, fmaxf(0.f, rintf((v.x - mn) / s)));
        int k1 = (int)fminf(255.f, fmaxf(0.f, rintf((v.y - mn) / s)));
        int k2 = (int)fminf(255.f, fmaxf(0.f, rintf((v.z - mn) / s)));
        int k3 = (int)fminf(255.f, fmaxf(0.f, rintf((v.w - mn) / s)));
        unsigned p = ((unsigned)((k0 - 128) & 0xff)) | ((unsigned)((k1 - 128) & 0xff) << 8) |
                     ((unsigned)((k2 - 128) & 0xff) << 16) | ((unsigned)((k3 - 128) & 0xff) << 24);
        *(unsigned*)(W8 + (size_t)prow * 2048 + tsel * 1024 + t * 4) = p;
        int sum = block_reduce_i(k0 + k1 + k2 + k3 - 512, t);
        if (t == 0) (tsel ? Rbh : Rbi)[prow] = (float)sum;
    } else {
        int n = (b - 24576) * 256 + t;   // permuted col index
        int j = (n >> 6) * 16 + (n & 15);
        int g = (n >> 4) & 3;
        bc[n] = b_in[g * 1024 + j] + b_h[g * 1024 + j];
    }
}

// ------------ fused i8 GEMM + LSTM pointwise (256x256, 8-PHASE) -------------
// Geometry (= R12): 256x256 tile, 512 thr = 8 waves (2M x 4N), wave 128x64 =
// 8x4 frags of 16x16, mfma_i32_16x16x64_i8, K-step = 64 B, 32 K-steps.
// Single accumulator + mid-K rescale acc=rint(r*acc) at step 16 (R11-exact).
// Schedule = m201 8-phase template: iteration = 2 K-steps from dbuf d=i&1,
// staging next 2 K-steps into dbuf d^1 spread 1 half-tile per phase. Phase =
// {ds_read subtile, 1 global_load_lds, barrier, lgkmcnt(0), setprio(1),
//  8 MFMA, setprio(0), barrier}. Counted vmcnt(4) ONLY at phases 4/8:
// entering iter i outstanding = step(2i+1)'s 4 loads; p3 gate retires them
// (oldest-first), p7 gate retires step(2i+2)'s. Own-vmcnt + barrier covers
// all waves (uniform issue order). Tail: i==15 p3 gate = vmcnt(0), no p7 gate.
// LDS 2 x 2step x 2half x 8KB x {A,B} = 128 KB. Swizzle (0-conflict
// validated): phys 16B slot = logical ^ ((row>>1)&3); inverse on global
// source (linear gload_lds dest, rule #21), forward on ds_read.
// XCD decode: xcd=bid&7 owns 4-M-tile slab; bx sweeps slow (B-panel reuse).
__global__ __launch_bounds__(512, 2) void k_gemm_lstm(
    const s8* __restrict__ A8, const s8* __restrict__ W8,
    const float* __restrict__ params, const float* __restrict__ bc,
    const float* __restrict__ Rax, const float* __restrict__ Rah,
    const float* __restrict__ Rbi, const float* __restrict__ Rbh,
    const float* __restrict__ c_in, float* __restrict__ out) {
    __shared__ __align__(16) s8 As[65536];   // [dbuf][steplo][half][8192]
    __shared__ __align__(16) s8 Bs[65536];

    const int tid = threadIdx.x;
    const int wave = tid >> 6, lane = tid & 63;
    const int wr = wave >> 2, wc = wave & 3;     // 2x4 wave grid
    const int la = lane & 15, hi = lane >> 4;

    const int bid = blockIdx.x;
    const int xcd = bid & 7, l = bid >> 3;
    const int bx = l >> 2;                       // 0..15 (N tile, slow)
    const int by = xcd * 4 + (l & 3);            // 0..31 (M tile)
    const int bm = by * 256, bn = bx * 256;

    const int skb = (((tid & 3) ^ ((tid >> 3) & 3)) * 16);   // staging swizzle
    const int rx = ((hi ^ ((la >> 1) & 3)) * 16);            // read swizzle
    const int bh = wc >> 1;                                  // B half
    const int br = (wc & 1) * 64 + la;                       // B row base in half

    const float sa = params[1], sh = params[3], si = params[5], sw = params[7];
    const float csx = sa * si, csh = sh * sw;
    const float r = csx / csh;

    // staging sources: thread covers row tid>>2 (half0) / +128 (half1)
    const s8* pA0 = A8 + (size_t)(bm + (tid >> 2)) * 2048 + skb;
    const s8* pA1 = pA0 + (size_t)128 * 2048;
    const s8* pB0 = W8 + (size_t)(bn + (tid >> 2)) * 2048 + skb;
    const s8* pB1 = pB0 + (size_t)128 * 2048;

    i32x4 acc[8][4];
#pragma unroll
    for (int m = 0; m < 8; m++)
#pragma unroll
        for (int n = 0; n < 4; n++) acc[m][n] = (i32x4)0;

    i32x4 a[8], b[4];

#define STGA(D, SL, H, TS)                                                                        \
    __builtin_amdgcn_global_load_lds(                                                             \
        (const __attribute__((address_space(1))) void*)(((H) ? pA1 : pA0) + (TS) * 64),           \
        (__attribute__((address_space(3))) void*)(As + (D) * 32768 + (SL) * 16384 + (H) * 8192 + tid * 16), \
        16, 0, 0)
#define STGB(D, SL, H, TS)                                                                        \
    __builtin_amdgcn_global_load_lds(                                                             \
        (const __attribute__((address_space(1))) void*)(((H) ? pB1 : pB0) + (TS) * 64),           \
        (__attribute__((address_space(3))) void*)(Bs + (D) * 32768 + (SL) * 16384 + (H) * 8192 + tid * 16), \
        16, 0, 0)
#define RDA4(D, SL, MLO)                                                                          \
    do { _Pragma("unroll") for (int mm = 0; mm < 4; ++mm)                                         \
        a[(MLO) + mm] = *(const i32x4*)(As + (D) * 32768 + (SL) * 16384 + wr * 8192 +             \
                                        (((MLO) + mm) * 16 + la) * 64 + rx); } while (0)
#define RDB2(D, SL, NLO)                                                                          \
    do { _Pragma("unroll") for (int nn = 0; nn < 2; ++nn)                                         \
        b[(NLO) + nn] = *(const i32x4*)(Bs + (D) * 32768 + (SL) * 16384 + bh * 8192 +             \
                                        (br + ((NLO) + nn) * 16) * 64 + rx); } while (0)
#define MM8(MLO, NLO)                                                                             \
    do { _Pragma("unroll") for (int mm = 0; mm < 4; ++mm)                                         \
        _Pragma("unroll") for (int nn = 0; nn < 2; ++nn)                                          \
            acc[(MLO) + mm][(NLO) + nn] = __builtin_amdgcn_mfma_i32_16x16x64_i8(                  \
                a[(MLO) + mm], b[(NLO) + nn], acc[(MLO) + mm][(NLO) + nn], 0, 0, 0); } while (0)
#define VM4 asm volatile("s_waitcnt vmcnt(4)" ::: "memory")
#define VM0 asm volatile("s_waitcnt vmcnt(0)" ::: "memory")
#define LGK0 asm volatile("s_waitcnt lgkmcnt(0)" ::: "memory")
#define BAR __builtin_amdgcn_s_barrier()
#define PRIO1 __builtin_amdgcn_s_setprio(1)
#define PRIO0 __builtin_amdgcn_s_setprio(0)

    // prologue: stage steps 0,1 into dbuf 0 (order = steady-state order)
    STGA(0, 0, 0, 0); STGA(0, 0, 1, 0); STGB(0, 0, 0, 0); STGB(0, 0, 1, 0);
    STGA(0, 1, 0, 1); STGA(0, 1, 1, 1); STGB(0, 1, 0, 1); STGB(0, 1, 1, 1);
    VM4;
    BAR;

#pragma unroll
    for (int i = 0; i < 16; ++i) {
        const int d = i & 1;
        const int ts0 = 2 * i + 2, ts1 = 2 * i + 3;   // steps staged this iter
        const bool stg = (i < 15);
        if (i == 8) {
            // fold x-half into h-half scale: acc = rint(r * acc)
#pragma unroll
            for (int m = 0; m < 8; m++)
#pragma unroll
                for (int n = 0; n < 4; n++)
#pragma unroll
                    for (int q = 0; q < 4; q++)
                        acc[m][n][q] = (int)rintf((float)acc[m][n][q] * r);
        }
        // ---- phases 0-3: compute K-step 2i (steplo 0), stage step ts0 ----
        RDA4(d, 0, 0); RDB2(d, 0, 0);
        if (stg) STGA(d ^ 1, 0, 0, ts0);
        BAR; LGK0; PRIO1; MM8(0, 0); PRIO0; BAR;

        RDB2(d, 0, 2);
        if (stg) STGA(d ^ 1, 0, 1, ts0);
        BAR; LGK0; PRIO1; MM8(0, 2); PRIO0; BAR;

        RDA4(d, 0, 4);
        if (stg) STGB(d ^ 1, 0, 0, ts0);
        BAR; LGK0; PRIO1; MM8(4, 0); PRIO0; BAR;

        if (stg) STGB(d ^ 1, 0, 1, ts0);
        BAR; PRIO1; MM8(4, 2); PRIO0;
        if (i < 15) { VM4; } else { VM0; }
        BAR;

        // ---- phases 4-7: compute K-step 2i+1 (steplo 1), stage step ts1 ----
        RDA4(d, 1, 0); RDB2(d, 1, 0);
        if (stg) STGA(d ^ 1, 1, 0, ts1);
        BAR; LGK0; PRIO1; MM8(0, 0); PRIO0; BAR;

        RDB2(d, 1, 2);
        if (stg) STGA(d ^ 1, 1, 1, ts1);
        BAR; LGK0; PRIO1; MM8(0, 2); PRIO0; BAR;

        RDA4(d, 1, 4);
        if (stg) STGB(d ^ 1, 1, 0, ts1);
        BAR; LGK0; PRIO1; MM8(4, 0); PRIO0; BAR;

        if (stg) STGB(d ^ 1, 1, 1, ts1);
        BAR; PRIO1; MM8(4, 2); PRIO0;
        if (i < 15) { VM4; BAR; }
    }

#undef STGA
#undef STGB
#undef RDA4
#undef RDB2
#undef MM8
#undef VM4
#undef VM0
#undef LGK0
#undef BAR
#undef PRIO1
#undef PRIO0

    // ---- epilogue: reconstruct gates from integer sums, LSTM pointwise ----
    float mna = params[0], mnh = params[2], mni = params[4], mnw = params[6];
    float za = mna + 128.0f * sa, zi = mni + 128.0f * si;
    float zh = mnh + 128.0f * sh, zw = mnw + 128.0f * sw;
    float C0 = 1024.0f * (za * zi + zh * zw);
    float cax = sa * zi, cah = sh * zw;
    float cbx = si * za, cbh = sw * zh;

    const int nb = bn + wc * 64;
    float colt[4];
#pragma unroll
    for (int g = 0; g < 4; ++g) {
        int np = nb + g * 16 + la;
        colt[g] = bc[np] + cbx * Rbi[np] + cbh * Rbh[np] + C0;
    }
    const int ub = (nb >> 6) * 16 + la;   // hidden-unit index

#pragma unroll
    for (int m = 0; m < 8; m++) {
#pragma unroll
        for (int q = 0; q < 4; q++) {
            int row = bm + wr * 128 + m * 16 + 4 * hi + q;
            float rterm = cax * Rax[row] + cah * Rah[row];
            float g0 = colt[0] + rterm + csh * (float)acc[m][0][q];
            float g1 = colt[1] + rterm + csh * (float)acc[m][1][q];
            float g2 = colt[2] + rterm + csh * (float)acc[m][2][q];
            float g3 = colt[3] + rterm + csh * (float)acc[m][3][q];
            float iv = 1.0f / (1.0f + __expf(-g0));
            float fv = 1.0f / (1.0f + __expf(-g1));
            float gv = tanhf(g2);
            float ov = 1.0f / (1.0f + __expf(-g3));
            size_t off = (size_t)row * 1024 + ub;
            float cv = c_in[off];
            float cn = fv * cv + iv * gv;
            float hn = ov * tanhf(cn);
            out[off] = hn;
            out[(size_t)8192 * 1024 + off] = cn;
        }
    }
}

extern "C" void kernel_launch(void* const* d_in, const int* in_sizes, int n_in,
                              void* d_out, int out_size, void* d_ws, size_t ws_size,
                              hipStream_t stream) {
    const float* x = (const float*)d_in[0];
    const float* h = (const float*)d_in[1];
    const float* c = (const float*)d_in[2];
    const float* wi = (const float*)d_in[3];
    const float* bi = (const float*)d_in[4];
    const float* wh = (const float*)d_in[5];
    const float* bh = (const float*)d_in[6];
    const int* nbits = (const int*)d_in[7];
    float* out = (float*)d_out;

    char* ws = (char*)d_ws;
    float* params   = (float*)ws;                   // 8 f32
    float* partials = (float*)(ws + 64);            // 4*256*2 f32
    float* bc  = (float*)(ws + 16384);              // 4096 f32
    float* Rax = (float*)(ws + 32768);              // 8192 f32
    float* Rah = (float*)(ws + 65536);              // 8192 f32
    float* Rbi = (float*)(ws + 98304);              // 4096 f32
    float* Rbh = (float*)(ws + 114688);             // 4096 f32
    s8* A8 = (s8*)(ws + 131072);                    // 8192*2048 i8 = 16MB
    s8* W8 = (s8*)(ws + 131072 + (size_t)16 * 1024 * 1024);  // 4096*2048 i8 = 8MB

    k_minmax_partial<<<dim3(NB_RED, 4), 256, 0, stream>>>(x, h, wi, wh, partials);
    k_minmax_final<<<4, 256, 0, stream>>>(partials, nbits, params);
    k_quant<<<24592, 256, 0, stream>>>(x, h, wi, wh, params, bi, bh,
                                       A8, W8, Rax, Rah, Rbi, Rbh, bc);
    k_gemm_lstm<<<512, 512, 0, stream>>>(A8, W8, params, bc, Rax, Rah, Rbi, Rbh, c, out);
}

// Round 14
// 133.124 us; speedup vs baseline: 1.1391x; 1.1391x over previous
//
#include <hip/hip_runtime.h>
#include <hip/hip_bf16.h>

typedef unsigned short u16;
typedef int i32x4 __attribute__((ext_vector_type(4)));
typedef signed char s8;

#define NB_RED 256

// ---------------- min/max reduction (4 tensors) ----------------
__global__ void k_minmax_partial(const float* __restrict__ x, const float* __restrict__ h,
                                 const float* __restrict__ wi, const float* __restrict__ wh,
                                 float* __restrict__ partials) {
    int t = blockIdx.y;
    const float* p = (t == 0) ? x : (t == 1) ? h : (t == 2) ? wi : wh;
    int n4 = ((t < 2) ? (8192 * 1024) : (4096 * 1024)) >> 2;
    float mn = 3.4e38f, mx = -3.4e38f;
    const float4* p4 = (const float4*)p;
    for (int i = blockIdx.x * blockDim.x + threadIdx.x; i < n4; i += gridDim.x * blockDim.x) {
        float4 v = p4[i];
        mn = fminf(mn, fminf(fminf(v.x, v.y), fminf(v.z, v.w)));
        mx = fmaxf(mx, fmaxf(fmaxf(v.x, v.y), fmaxf(v.z, v.w)));
    }
    for (int d = 1; d < 64; d <<= 1) {
        mn = fminf(mn, __shfl_xor(mn, d));
        mx = fmaxf(mx, __shfl_xor(mx, d));
    }
    __shared__ float smn[4], smx[4];
    int wv = threadIdx.x >> 6;
    if ((threadIdx.x & 63) == 0) { smn[wv] = mn; smx[wv] = mx; }
    __syncthreads();
    if (threadIdx.x == 0) {
        mn = fminf(fminf(smn[0], smn[1]), fminf(smn[2], smn[3]));
        mx = fmaxf(fmaxf(smx[0], smx[1]), fmaxf(smx[2], smx[3]));
        partials[(t * NB_RED + blockIdx.x) * 2 + 0] = mn;
        partials[(t * NB_RED + blockIdx.x) * 2 + 1] = mx;
    }
}

__global__ void k_minmax_final(const float* __restrict__ partials, const int* __restrict__ nbits,
                               float* __restrict__ params) {
    int t = blockIdx.x;
    int tid = threadIdx.x;
    float mn = partials[(t * NB_RED + tid) * 2 + 0];
    float mx = partials[(t * NB_RED + tid) * 2 + 1];
    for (int d = 1; d < 64; d <<= 1) {
        mn = fminf(mn, __shfl_xor(mn, d));
        mx = fmaxf(mx, __shfl_xor(mx, d));
    }
    __shared__ float smn[4], smx[4];
    int wv = tid >> 6;
    if ((tid & 63) == 0) { smn[wv] = mn; smx[wv] = mx; }
    __syncthreads();
    if (tid == 0) {
        mn = fminf(fminf(smn[0], smn[1]), fminf(smn[2], smn[3]));
        mx = fmaxf(fmaxf(smx[0], smx[1]), fmaxf(smx[2], smx[3]));
        float qmax = (float)((1u << (*nbits)) - 1u);
        params[t * 2 + 0] = mn;
        params[t * 2 + 1] = (mx - mn) / qmax;
    }
}

static __device__ __forceinline__ int block_reduce_i(int v, int tid) {
    for (int d = 1; d < 64; d <<= 1) v += __shfl_xor(v, d);
    __shared__ int sred[4];
    if ((tid & 63) == 0) sred[tid >> 6] = v;
    __syncthreads();
    return sred[0] + sred[1] + sred[2] + sred[3];
}

// ---- fused quantize (x|h -> A8, W_in|W_h -> W8 permuted) + bias ----
// blocks [0,16384): A rows; [16384,24576): W rows; [24576,24592): bias.
__global__ void k_quant(const float* __restrict__ x, const float* __restrict__ h,
                        const float* __restrict__ wi, const float* __restrict__ wh,
                        const float* __restrict__ params,
                        const float* __restrict__ b_in, const float* __restrict__ b_h,
                        s8* __restrict__ A8, s8* __restrict__ W8,
                        float* __restrict__ Rax, float* __restrict__ Rah,
                        float* __restrict__ Rbi, float* __restrict__ Rbh,
                        float* __restrict__ bc) {
    int b = blockIdx.x;
    int t = threadIdx.x;
    if (b < 16384) {
        int tsel = b >> 13;            // 0: x, 1: h
        int row = b & 8191;
        const float* src = tsel ? h : x;
        float mn = params[tsel * 2 + 0], s = params[tsel * 2 + 1];
        float4 v = ((const float4*)(src + (size_t)row * 1024))[t];
        int k0 = (int)fminf(255.f, fmaxf(0.f, rintf((v.x - mn) / s)));
        int k1 = (int)fminf(255.f, fmaxf(0.f, rintf((v.y - mn) / s)));
        int k2 = (int)fminf(255.f, fmaxf(0.f, rintf((v.z - mn) / s)));
        int k3 = (int)fminf(255.f, fmaxf(0.f, rintf((v.w - mn) / s)));
        unsigned p = ((unsigned)((k0 - 128) & 0xff)) | ((unsigned)((k1 - 128) & 0xff) << 8) |
                     ((unsigned)((k2 - 128) & 0xff) << 16) | ((unsigned)((k3 - 128) & 0xff) << 24);
        *(unsigned*)(A8 + (size_t)row * 2048 + tsel * 1024 + t * 4) = p;
        int sum = block_reduce_i(k0 + k1 + k2 + k3 - 512, t);
        if (t == 0) (tsel ? Rah : Rax)[row] = (float)sum;
    } else if (b < 24576) {
        int bb = b - 16384;
        int tsel = bb >> 12;           // 0: W_in, 1: W_h
        int row = bb & 4095;           // original row g*1024+j
        const float* src = tsel ? wh : wi;
        float mn = params[(2 + tsel) * 2 + 0], s = params[(2 + tsel) * 2 + 1];
        int g = row >> 10, j = row & 1023;
        int prow = (j >> 4) * 64 + g * 16 + (j & 15);
        float4 v = ((const float4*)(src + (size_t)row * 1024))[t];
        int k0 = (int)fminf(255.f, fmaxf(0.f, rintf((v.x - mn) / s)));
        int k1 = (int)fminf(255.f, fmaxf(0.f, rintf((v.y - mn) / s)));
        int k2 = (int)fminf(255.f, fmaxf(0.f, rintf((v.z - mn) / s)));
        int k3 = (int)fminf(255.f, fmaxf(0.f, rintf((v.w - mn) / s)));
        unsigned p = ((unsigned)((k0 - 128) & 0xff)) | ((unsigned)((k1 - 128) & 0xff) << 8) |
                     ((unsigned)((k2 - 128) & 0xff) << 16) | ((unsigned)((k3 - 128) & 0xff) << 24);
        *(unsigned*)(W8 + (size_t)prow * 2048 + tsel * 1024 + t * 4) = p;
        int sum = block_reduce_i(k0 + k1 + k2 + k3 - 512, t);
        if (t == 0) (tsel ? Rbh : Rbi)[prow] = (float)sum;
    } else {
        int n = (b - 24576) * 256 + t;   // permuted col index
        int j = (n >> 6) * 16 + (n & 15);
        int g = (n >> 4) & 3;
        bc[n] = b_in[g * 1024 + j] + b_h[g * 1024 + j];
    }
}

// ---------- fused i8 GEMM + LSTM pointwise (128x256, 4 waves/SIMD) ----------
// 128x256 tile, 512 thr = 8 waves (2M x 4N), wave 64x64 = 4x4 frags 16x16,
// BK=64 bytes, mfma_i32_16x16x64_i8, 32 K-steps. Single accumulator (64 regs)
// + mid-K rescale acc=rint(r*acc) at t==16 (R11-exact, r=csx/csh); epilogue
// scales by csh. ~125 regs total -> __launch_bounds__(512,4): 4 waves/SIMD,
// 2 blocks/CU (cross-block m114 overlap + epilogue/compute overlap).
// LDS: 3-buffer ring x 24KB (A 8KB + B 16KB) = 72KB -> 2 blocks/CU fits.
// Schedule (R11/R12-proven): stage 2 tiles ahead (3 gload_lds/thread/tile),
// counted vmcnt(3) steady state, ONE s_barrier per K-step, vmcnt(0) at tail.
// Swizzle (0-conflict validated): phys 16B slot = logical ^ ((row>>1)&3);
// inverse on global source (linear gload_lds dest, rule #21), fwd on ds_read.
// XCD decode (grid 1024): xcd=bid&7 owns 8 M-tiles (2MB A-slice, L2-resident);
// bx sweeps slow -> B-panel (512KB) reused by 8 consecutive same-XCD blocks.
__global__ __launch_bounds__(512, 4) void k_gemm_lstm(
    const s8* __restrict__ A8, const s8* __restrict__ W8,
    const float* __restrict__ params, const float* __restrict__ bc,
    const float* __restrict__ Rax, const float* __restrict__ Rah,
    const float* __restrict__ Rbi, const float* __restrict__ Rbh,
    const float* __restrict__ c_in, float* __restrict__ out) {
    __shared__ __align__(16) s8 As[3][8192];    // [buf][128 rows x 64B]
    __shared__ __align__(16) s8 Bs[3][16384];   // [buf][256 rows x 64B]

    const int tid = threadIdx.x;
    const int wave = tid >> 6, lane = tid & 63;
    const int wr = wave >> 2, wc = wave & 3;     // 2M x 4N wave grid
    const int la = lane & 15, hi = lane >> 4;

    // XCD-aware tile decode (grid = 1024; M-tiles 64, N-tiles 16)
    const int bid = blockIdx.x;
    const int l = bid >> 3;                      // 0..127
    const int bx = l >> 3;                       // 0..15 (N tile, slow)
    const int by = (bid & 7) * 8 + (l & 7);      // 0..63 (M tile)
    const int bm = by * 128, bn = bx * 256;

    const int skb = (((tid & 3) ^ ((tid >> 3) & 3)) * 16);   // staging swizzle
    const int rx = ((hi ^ ((la >> 1) & 3)) * 16);            // read swizzle

    const float sa = params[1], sh = params[3], si = params[5], sw = params[7];
    const float csx = sa * si, csh = sh * sw;
    const float r = csx / csh;

    // staging sources: A row tid>>2; B rows tid>>2 and 128+(tid>>2)
    const s8* pA0 = A8 + (size_t)(bm + (tid >> 2)) * 2048 + skb;
    const s8* pB0 = W8 + (size_t)(bn + (tid >> 2)) * 2048 + skb;
    const s8* pB1 = pB0 + (size_t)128 * 2048;

    i32x4 acc[4][4];
#pragma unroll
    for (int m = 0; m < 4; m++)
#pragma unroll
        for (int n = 0; n < 4; n++) acc[m][n] = (i32x4)0;

#define STAGE(B, T)                                                                               \
    do {                                                                                          \
        __builtin_amdgcn_global_load_lds(                                                         \
            (const __attribute__((address_space(1))) void*)(pA0 + (T) * 64),                      \
            (__attribute__((address_space(3))) void*)&As[(B)][tid * 16], 16, 0, 0);               \
        __builtin_amdgcn_global_load_lds(                                                         \
            (const __attribute__((address_space(1))) void*)(pB0 + (T) * 64),                      \
            (__attribute__((address_space(3))) void*)&Bs[(B)][tid * 16], 16, 0, 0);               \
        __builtin_amdgcn_global_load_lds(                                                         \
            (const __attribute__((address_space(1))) void*)(pB1 + (T) * 64),                      \
            (__attribute__((address_space(3))) void*)&Bs[(B)][8192 + tid * 16], 16, 0, 0);        \
    } while (0)

#define COMPUTE(B)                                                                                \
    do {                                                                                          \
        i32x4 af[4], bf[4];                                                                       \
        _Pragma("unroll") for (int m = 0; m < 4; m++)                                             \
            af[m] = *(const i32x4*)&As[(B)][(wr * 64 + m * 16 + la) * 64 + rx];                   \
        _Pragma("unroll") for (int n = 0; n < 4; n++)                                             \
            bf[n] = *(const i32x4*)&Bs[(B)][(wc * 64 + n * 16 + la) * 64 + rx];                   \
        _Pragma("unroll") for (int m = 0; m < 4; m++)                                             \
            _Pragma("unroll") for (int n = 0; n < 4; n++)                                         \
                acc[m][n] = __builtin_amdgcn_mfma_i32_16x16x64_i8(af[m], bf[n], acc[m][n], 0, 0, 0); \
    } while (0)

    // prologue: tiles 0,1 in flight (6 loads/thread); wait tile 0 (leave 3)
    STAGE(0, 0);
    STAGE(1, 1);
    asm volatile("s_waitcnt vmcnt(3)" ::: "memory");
    __builtin_amdgcn_s_barrier();

#pragma unroll
    for (int t = 0; t < 32; ++t) {
        if (t < 30) STAGE((t + 2) % 3, t + 2);
        if (t == 16) {
            // fold x-half into h-half scale: acc = rint(r * acc)
#pragma unroll
            for (int m = 0; m < 4; m++)
#pragma unroll
                for (int n = 0; n < 4; n++)
#pragma unroll
                    for (int q = 0; q < 4; q++)
                        acc[m][n][q] = (int)rintf((float)acc[m][n][q] * r);
        }
        COMPUTE(t % 3);
        if (t < 30) { asm volatile("s_waitcnt vmcnt(3)" ::: "memory"); }
        else if (t == 30) { asm volatile("s_waitcnt vmcnt(0)" ::: "memory"); }
        if (t < 31) __builtin_amdgcn_s_barrier();
    }

#undef STAGE
#undef COMPUTE

    // ---- epilogue: reconstruct gates from integer sums, LSTM pointwise ----
    float mna = params[0], mnh = params[2], mni = params[4], mnw = params[6];
    float za = mna + 128.0f * sa, zi = mni + 128.0f * si;
    float zh = mnh + 128.0f * sh, zw = mnw + 128.0f * sw;
    float C0 = 1024.0f * (za * zi + zh * zw);
    float cax = sa * zi, cah = sh * zw;
    float cbx = si * za, cbh = sw * zh;

    const int nb = bn + wc * 64;
    float colt[4];
#pragma unroll
    for (int g = 0; g < 4; ++g) {
        int np = nb + g * 16 + la;
        colt[g] = bc[np] + cbx * Rbi[np] + cbh * Rbh[np] + C0;
    }
    const int ub = (nb >> 6) * 16 + la;   // hidden-unit index

#pragma unroll
    for (int m = 0; m < 4; m++) {
#pragma unroll
        for (int q = 0; q < 4; q++) {
            int row = bm + wr * 64 + m * 16 + 4 * hi + q;
            float rterm = cax * Rax[row] + cah * Rah[row];
            float g0 = colt[0] + rterm + csh * (float)acc[m][0][q];
            float g1 = colt[1] + rterm + csh * (float)acc[m][1][q];
            float g2 = colt[2] + rterm + csh * (float)acc[m][2][q];
            float g3 = colt[3] + rterm + csh * (float)acc[m][3][q];
            float iv = 1.0f / (1.0f + __expf(-g0));
            float fv = 1.0f / (1.0f + __expf(-g1));
            float gv = tanhf(g2);
            float ov = 1.0f / (1.0f + __expf(-g3));
            size_t off = (size_t)row * 1024 + ub;
            float cv = c_in[off];
            float cn = fv * cv + iv * gv;
            float hn = ov * tanhf(cn);
            out[off] = hn;
            out[(size_t)8192 * 1024 + off] = cn;
        }
    }
}

extern "C" void kernel_launch(void* const* d_in, const int* in_sizes, int n_in,
                              void* d_out, int out_size, void* d_ws, size_t ws_size,
                              hipStream_t stream) {
    const float* x = (const float*)d_in[0];
    const float* h = (const float*)d_in[1];
    const float* c = (const float*)d_in[2];
    const float* wi = (const float*)d_in[3];
    const float* bi = (const float*)d_in[4];
    const float* wh = (const float*)d_in[5];
    const float* bh = (const float*)d_in[6];
    const int* nbits = (const int*)d_in[7];
    float* out = (float*)d_out;

    char* ws = (char*)d_ws;
    float* params   = (float*)ws;                   // 8 f32
    float* partials = (float*)(ws + 64);            // 4*256*2 f32
    float* bc  = (float*)(ws + 16384);              // 4096 f32
    float* Rax = (float*)(ws + 32768);              // 8192 f32
    float* Rah = (float*)(ws + 65536);              // 8192 f32
    float* Rbi = (float*)(ws + 98304);              // 4096 f32
    float* Rbh = (float*)(ws + 114688);             // 4096 f32
    s8* A8 = (s8*)(ws + 131072);                    // 8192*2048 i8 = 16MB
    s8* W8 = (s8*)(ws + 131072 + (size_t)16 * 1024 * 1024);  // 4096*2048 i8 = 8MB

    k_minmax_partial<<<dim3(NB_RED, 4), 256, 0, stream>>>(x, h, wi, wh, partials);
    k_minmax_final<<<4, 256, 0, stream>>>(partials, nbits, params);
    k_quant<<<24592, 256, 0, stream>>>(x, h, wi, wh, params, bi, bh,
                                       A8, W8, Rax, Rah, Rbi, Rbh, bc);
    k_gemm_lstm<<<1024, 512, 0, stream>>>(A8, W8, params, bc, Rax, Rah, Rbi, Rbh, c, out);
}